// Round 6
// baseline (498.795 us; speedup 1.0000x reference)
//
#include <hip/hip_runtime.h>
#include <math.h>

// ConvGRU scan, bf16 MFMA 16x16x32, 128 blocks x 512 threads (8 waves).
// B-fragment sharing: each wave computes ALL 32 output channels (both
// 16-co mtiles) per spatial tile, and w0/1 pair u1+r1 (same B source), so
// every ds_read_b128 feeds 2-4 MFMAs. Reads/step: 432 -> 180.
// Roles: w0/1 u1+r1 | w2/3 u2 | w4/5 r2 | w6/7 o1+o2. Stile pair = w&1.
// All LDS layouts identical to the verified round-5 kernel.

#define TT 64
#define NB 128
#define CC 32
#define AA 8
#define SS 49
#define HH 1568
#define KK 288      // 9 taps * 32 channels, all six convs
#define NKB 9
#define NPOS 81
#define NTHR 512

typedef short bf16x8 __attribute__((ext_vector_type(8)));
typedef short bf16x4 __attribute__((ext_vector_type(4)));
typedef float f32x4 __attribute__((ext_vector_type(4)));

struct __align__(16) SMEM {
  union {
    short staging[CC * KK];             // 9216 shorts weight scratch
    struct {
      short stacked[NPOS * CC];         // prev (or prev*r), swizzled
      short img_u[NPOS * CC];           // u1 / o1 relu output
      short img_r[NPOS * CC];           // r1 relu output
    } im;
  } u;
  short wsum[3 * 9 * CC * AA];          // bf16 class-summed inp weights [g][cls][co][ci]
  short cArr[3 * 9 * CC];               // per-step inp term + conv1 bias [g][cls][co]
  float sH[HH];
  float sU[HH];
  float sO[HH];
  float bias[6 * CC];                   // bu1,bu2,br1,br2,bo1,bo2
};

__device__ __forceinline__ short f2bf(float v) {
  union { float f; unsigned u; } a; a.f = v;
  unsigned r = a.u + 0x7FFFu + ((a.u >> 16) & 1u);
  return (short)(r >> 16);
}
__device__ __forceinline__ float b2f(short h) {
  union { unsigned u; float f; } a; a.u = ((unsigned)(unsigned short)h) << 16;
  return a.f;
}
__device__ __forceinline__ float sigm(float v) { return 1.f / (1.f + __expf(-v)); }
__device__ __forceinline__ float tanhfast(float v) { return 2.f / (1.f + __expf(-2.f * v)) - 1.f; }

__device__ __forceinline__ int swz(int p, int ci) {
  return ((p << 5) + ci) ^ (((p >> 1) & 3) << 3);
}
__device__ __forceinline__ int clsOf(int s) {
  int y = s / 7, x = s - y * 7;
  return (y == 0 ? 0 : (y == 6 ? 6 : 3)) + (x == 0 ? 0 : (x == 6 ? 2 : 1));
}

#define MFMA(A, B, C) __builtin_amdgcn_mfma_f32_16x16x32_bf16((A), (B), (C), 0, 0, 0)

__global__ __launch_bounds__(NTHR, 2)
void convgru_mfma(const float* __restrict__ x, const float* __restrict__ hxs,
                  const float* __restrict__ att, const float* __restrict__ masks,
                  const float* __restrict__ pact,
                  const float* __restrict__ Wr1, const float* __restrict__ br1,
                  const float* __restrict__ Wr2, const float* __restrict__ br2,
                  const float* __restrict__ Wu1, const float* __restrict__ bu1,
                  const float* __restrict__ Wu2, const float* __restrict__ bu2,
                  const float* __restrict__ Wo1, const float* __restrict__ bo1,
                  const float* __restrict__ Wo2, const float* __restrict__ bo2,
                  float* __restrict__ out)
{
  __shared__ SMEM sm;
  const int n = blockIdx.x;
  const int tid = threadIdx.x;
  const int w = __builtin_amdgcn_readfirstlane(tid >> 6);
  const int lane = tid & 63;
  const int role = w >> 1;            // 0: u1+r1 | 1: u2 | 2: r2 | 3: o1+o2
  const int b2 = w & 1;               // stile pair: {2*b2, 2*b2+1}
  const int fg = lane >> 4;
  const int col = lane & 15;

  // ---- bias staging
  if (tid < 6 * CC) {
    const float* bsrc[6] = {bu1, bu2, br1, br2, bo1, bo2};
    sm.bias[tid] = bsrc[tid >> 5][tid & 31];
  }

  // ---- weight transpose staging + per-role A-frag preload (k = tap*32 + pc)
  // fA slots: role0: [u1m0,u1m1,r1m0,r1m1]  role1: [u2m0,u2m1,-,-]
  //           role2: [r2m0,r2m1,-,-]        role3: [o1m0,o1m1,o2m0,o2m1]
  bf16x8 fA[4][NKB];
  {
    const float* wsrc[6] = {Wu1, Wr1, Wo1, Wu2, Wr2, Wo2};
#pragma unroll
    for (int cv = 0; cv < 6; ++cv) {
      __syncthreads();
      const float* wp = wsrc[cv];
      const int cin = (cv < 3) ? (AA + CC) : CC;
      const int cofs = (cv < 3) ? AA : 0;
      for (int i = tid; i < CC * KK; i += NTHR) {
        int co = i / KK, k = i - co * KK;
        int tap = k >> 5, pc = k & 31;
        sm.u.staging[(co * KK + k) ^ ((co & 7) << 3)] =
            f2bf(wp[(co * cin + cofs + pc) * 9 + tap]);
      }
      __syncthreads();
      auto loadfr = [&](bf16x8 (&dst)[NKB], int mt) {
        const int fco = mt * 16 + col;
#pragma unroll
        for (int b = 0; b < NKB; ++b)
          dst[b] = *(const bf16x8*)&sm.u.staging[(fco * KK + b * 32 + fg * 8) ^ ((fco & 7) << 3)];
      };
      if (cv == 0 && role == 0) { loadfr(fA[0], 0); loadfr(fA[1], 1); }
      if (cv == 1 && role == 0) { loadfr(fA[2], 0); loadfr(fA[3], 1); }
      if (cv == 2 && role == 3) { loadfr(fA[0], 0); loadfr(fA[1], 1); }
      if (cv == 3 && role == 1) { loadfr(fA[0], 0); loadfr(fA[1], 1); }
      if (cv == 4 && role == 2) { loadfr(fA[0], 0); loadfr(fA[1], 1); }
      if (cv == 5 && role == 3) { loadfr(fA[2], 0); loadfr(fA[3], 1); }
    }
  }
  __syncthreads();

  // ---- zero images (borders stay 0) + Wsum compute (disjoint regions)
  for (int i = tid; i < CC * KK; i += NTHR) sm.u.staging[i] = 0;
  {
    const float* w1s[3] = {Wu1, Wr1, Wo1};
    for (int e = tid; e < 3 * 9 * CC * AA; e += NTHR) {
      int g = e / 2304, rem = e - g * 2304;
      int cls = rem >> 8;
      int co = (rem >> 3) & 31, ci = e & 7;
      int yt = cls / 3, xt = cls - yt * 3;
      const float* wp = w1s[g] + (co * (AA + CC) + ci) * 9;
      float s = 0.f;
#pragma unroll
      for (int r = 0; r < 3; ++r) {
        if ((yt == 0 && r == 0) || (yt == 2 && r == 2)) continue;
#pragma unroll
        for (int c = 0; c < 3; ++c) {
          if ((xt == 0 && c == 0) || (xt == 2 && c == 2)) continue;
          s += wp[r * 3 + c];
        }
      }
      sm.wsum[e] = f2bf(s);
    }
  }

  // ---- per-lane spatial precompute (t-invariant, swizzled)
  int sg[2], clsJ[2], inJ[2][NKB], poutJ[2][2]; bool vJ[2];
#pragma unroll
  for (int j = 0; j < 2; ++j) {
    int s = (b2 * 2 + j) * 16 + col;
    vJ[j] = (s < SS); int sc = vJ[j] ? s : (SS - 1); sg[j] = sc;
    int y = sc / 7, xx = sc - y * 7;
    int p0 = y * 9 + xx;
    clsJ[j] = clsOf(sc);
#pragma unroll
    for (int mt = 0; mt < 2; ++mt)
      poutJ[j][mt] = swz(p0 + 10, mt * 16 + fg * 4);
#pragma unroll
    for (int b = 0; b < NKB; ++b)
      inJ[j][b] = swz(p0 + (b / 3) * 9 + (b % 3), fg * 8);
  }

  // ---- epilogue precompute
  int eidx[4], stSw[4]; bool eval[4];
#pragma unroll
  for (int j = 0; j < 4; ++j) {
    int i = tid + j * NTHR;
    eval[j] = (i < HH);
    int ii = eval[j] ? i : 0;
    eidx[j] = ii;
    int co = ii / SS, s = ii - co * SS;
    int y = s / 7, xx = s - y * 7;
    stSw[j] = swz(y * 9 + xx + 10, co);
  }

  float* out_pmu = out;
  float* out_att = out + (size_t)TT * NB * HH;
  float* out_h   = out + (size_t)2 * TT * NB * HH;

  __syncthreads();

  // conv2 bias regs (role-dependent: u2 / r2 / o2)
  f32x4 bia2[2];
  {
    const int bb = (role == 2) ? 96 : (role == 3) ? 160 : 32;
#pragma unroll
    for (int mt = 0; mt < 2; ++mt)
#pragma unroll
      for (int q = 0; q < 4; ++q)
        bia2[mt][q] = sm.bias[bb + mt * 16 + fg * 4 + q];
  }

  // wsum + bias1 preload to regs for carr (owned by w2..w5)
  const bool carrOwn = (tid >= 128 && tid < 384);
  const int lt = tid - 128;
  bf16x8 wR[4]; float bR[4]; bool okC[4];
#pragma unroll
  for (int k = 0; k < 4; ++k) {
    int e = lt + 256 * k;
    okC[k] = carrOwn && (e < 3 * 9 * CC);
    if (okC[k]) {
      wR[k] = *(const bf16x8*)&sm.wsum[e << 3];
      bR[k] = sm.bias[((e / 288) << 6) + (e & 31)];
    }
  }

  auto carr = [&](const float (&v)[8]) {
#pragma unroll
    for (int k = 0; k < 4; ++k) if (okC[k]) {
      float acc = bR[k];
#pragma unroll
      for (int q = 0; q < 8; ++q) acc = fmaf(b2f(wR[k][q]), v[q], acc);
      sm.cArr[lt + 256 * k] = f2bf(acc);
    }
  };

  // ---- step-0 build
  float xcar[4];
  {
    const float m0 = masks[n];
    const float* x0 = x + (size_t)n * HH;
    const float* h0 = hxs + (size_t)n * HH;
#pragma unroll
    for (int j = 0; j < 4; ++j) if (eval[j]) {
      float xv = x0[eidx[j]];
      float h = h0[eidx[j]] * m0 + xv * (1.f - m0);
      sm.sH[eidx[j]] = h;
      sm.u.im.stacked[stSw[j]] = f2bf(h);
      xcar[j] = xv;
    }
    float v0[8];
    const float* pa0 = pact + (size_t)n * AA;
#pragma unroll
    for (int q = 0; q < 8; ++q) v0[q] = pa0[q] * m0;
    carr(v0);
  }
  __syncthreads();

  for (int t = 0; t < TT; ++t) {
    const bool last = (t == TT - 1);
    const size_t obase = ((size_t)(t * NB) + n) * HH;

    // prefetch: att(t), x(t+1), masks(t+1), pact(t+1) — consumed in P4/P5
    const float* atp = att + obase;
    const int tn = last ? t : (t + 1);
    const float* xnp = x + ((size_t)(tn * NB) + n) * HH;
    float xnv[4], avv[4];
#pragma unroll
    for (int j = 0; j < 4; ++j) { avv[j] = atp[eidx[j]]; xnv[j] = xnp[eidx[j]]; }
    const float m2 = last ? 0.f : masks[(t + 1) * NB + n];
    float vN[8];
    const float* pap = pact + ((size_t)(tn * NB) + n) * AA;
#pragma unroll
    for (int q = 0; q < 8; ++q) vN[q] = pap[q] * m2;

    // ---- P1: u1 + r1 (paired, shared B) on w0/w1; +cArr, relu
    if (role == 0) {
#pragma unroll
      for (int j = 0; j < 2; ++j) {
        bf16x8 bv[NKB];
#pragma unroll
        for (int b = 0; b < NKB; ++b)
          bv[b] = *(const bf16x8*)&sm.u.im.stacked[inJ[j][b]];
        f32x4 aU0 = {0.f,0.f,0.f,0.f}, aU1 = {0.f,0.f,0.f,0.f};
        f32x4 aR0 = {0.f,0.f,0.f,0.f}, aR1 = {0.f,0.f,0.f,0.f};
#pragma unroll
        for (int b = 0; b < NKB; ++b) {
          aU0 = MFMA(fA[0][b], bv[b], aU0);
          aU1 = MFMA(fA[1][b], bv[b], aU1);
          aR0 = MFMA(fA[2][b], bv[b], aR0);
          aR1 = MFMA(fA[3][b], bv[b], aR1);
        }
        if (vJ[j]) {
          bf16x4 c4, pk;
          // u, mt0 / mt1
          c4 = *(const bf16x4*)&sm.cArr[(clsJ[j] << 5) + fg * 4];
#pragma unroll
          for (int q = 0; q < 4; ++q) pk[q] = f2bf(fmaxf(aU0[q] + b2f(c4[q]), 0.f));
          *(bf16x4*)&sm.u.im.img_u[poutJ[j][0]] = pk;
          c4 = *(const bf16x4*)&sm.cArr[(clsJ[j] << 5) + 16 + fg * 4];
#pragma unroll
          for (int q = 0; q < 4; ++q) pk[q] = f2bf(fmaxf(aU1[q] + b2f(c4[q]), 0.f));
          *(bf16x4*)&sm.u.im.img_u[poutJ[j][1]] = pk;
          // r, mt0 / mt1
          c4 = *(const bf16x4*)&sm.cArr[((9 + clsJ[j]) << 5) + fg * 4];
#pragma unroll
          for (int q = 0; q < 4; ++q) pk[q] = f2bf(fmaxf(aR0[q] + b2f(c4[q]), 0.f));
          *(bf16x4*)&sm.u.im.img_r[poutJ[j][0]] = pk;
          c4 = *(const bf16x4*)&sm.cArr[((9 + clsJ[j]) << 5) + 16 + fg * 4];
#pragma unroll
          for (int q = 0; q < 4; ++q) pk[q] = f2bf(fmaxf(aR1[q] + b2f(c4[q]), 0.f));
          *(bf16x4*)&sm.u.im.img_r[poutJ[j][1]] = pk;
        }
      }
    }
    __syncthreads();

    // ---- P2: u2 (w2/3) -> sigmoid -> sU ; r2 (w4/5) -> sigmoid*prev -> stacked
    if (role == 1) {
#pragma unroll
      for (int j = 0; j < 2; ++j) {
        bf16x8 bv[NKB];
#pragma unroll
        for (int b = 0; b < NKB; ++b)
          bv[b] = *(const bf16x8*)&sm.u.im.img_u[inJ[j][b]];
        f32x4 a0 = {0.f,0.f,0.f,0.f}, a1 = {0.f,0.f,0.f,0.f};
#pragma unroll
        for (int b = 0; b < NKB; ++b) {
          a0 = MFMA(fA[0][b], bv[b], a0);
          a1 = MFMA(fA[1][b], bv[b], a1);
        }
        if (vJ[j]) {
#pragma unroll
          for (int q = 0; q < 4; ++q) {
            sm.sU[(fg * 4 + q) * SS + sg[j]]      = sigm(a0[q] + bia2[0][q]);
            sm.sU[(16 + fg * 4 + q) * SS + sg[j]] = sigm(a1[q] + bia2[1][q]);
          }
        }
      }
    } else if (role == 2) {
#pragma unroll
      for (int j = 0; j < 2; ++j) {
        bf16x8 bv[NKB];
#pragma unroll
        for (int b = 0; b < NKB; ++b)
          bv[b] = *(const bf16x8*)&sm.u.im.img_r[inJ[j][b]];
        f32x4 a0 = {0.f,0.f,0.f,0.f}, a1 = {0.f,0.f,0.f,0.f};
#pragma unroll
        for (int b = 0; b < NKB; ++b) {
          a0 = MFMA(fA[0][b], bv[b], a0);
          a1 = MFMA(fA[1][b], bv[b], a1);
        }
        if (vJ[j]) {
          bf16x4 pk;
#pragma unroll
          for (int q = 0; q < 4; ++q) {
            float rv = sigm(a0[q] + bia2[0][q]);
            pk[q] = f2bf(sm.sH[(fg * 4 + q) * SS + sg[j]] * rv);
          }
          *(bf16x4*)&sm.u.im.stacked[poutJ[j][0]] = pk;
#pragma unroll
          for (int q = 0; q < 4; ++q) {
            float rv = sigm(a1[q] + bia2[1][q]);
            pk[q] = f2bf(sm.sH[(16 + fg * 4 + q) * SS + sg[j]] * rv);
          }
          *(bf16x4*)&sm.u.im.stacked[poutJ[j][1]] = pk;
        }
      }
    }
    __syncthreads();

    // ---- P3: o1 on stacked2 (w6/7), +cArr, relu -> img_u
    if (role == 3) {
#pragma unroll
      for (int j = 0; j < 2; ++j) {
        bf16x8 bv[NKB];
#pragma unroll
        for (int b = 0; b < NKB; ++b)
          bv[b] = *(const bf16x8*)&sm.u.im.stacked[inJ[j][b]];
        f32x4 a0 = {0.f,0.f,0.f,0.f}, a1 = {0.f,0.f,0.f,0.f};
#pragma unroll
        for (int b = 0; b < NKB; ++b) {
          a0 = MFMA(fA[0][b], bv[b], a0);
          a1 = MFMA(fA[1][b], bv[b], a1);
        }
        if (vJ[j]) {
          bf16x4 c4, pk;
          c4 = *(const bf16x4*)&sm.cArr[((18 + clsJ[j]) << 5) + fg * 4];
#pragma unroll
          for (int q = 0; q < 4; ++q) pk[q] = f2bf(fmaxf(a0[q] + b2f(c4[q]), 0.f));
          *(bf16x4*)&sm.u.im.img_u[poutJ[j][0]] = pk;
          c4 = *(const bf16x4*)&sm.cArr[((18 + clsJ[j]) << 5) + 16 + fg * 4];
#pragma unroll
          for (int q = 0; q < 4; ++q) pk[q] = f2bf(fmaxf(a1[q] + b2f(c4[q]), 0.f));
          *(bf16x4*)&sm.u.im.img_u[poutJ[j][1]] = pk;
        }
      }
    }
    __syncthreads();

    // ---- P4: o2 (w6/7) -> tanh -> sO ; carr(t+1) on w2..w5 (idle here)
    if (role == 3) {
#pragma unroll
      for (int j = 0; j < 2; ++j) {
        bf16x8 bv[NKB];
#pragma unroll
        for (int b = 0; b < NKB; ++b)
          bv[b] = *(const bf16x8*)&sm.u.im.img_u[inJ[j][b]];
        f32x4 a0 = {0.f,0.f,0.f,0.f}, a1 = {0.f,0.f,0.f,0.f};
#pragma unroll
        for (int b = 0; b < NKB; ++b) {
          a0 = MFMA(fA[2][b], bv[b], a0);
          a1 = MFMA(fA[3][b], bv[b], a1);
        }
        if (vJ[j]) {
#pragma unroll
          for (int q = 0; q < 4; ++q) {
            sm.sO[(fg * 4 + q) * SS + sg[j]]      = tanhfast(a0[q] + bia2[0][q]);
            sm.sO[(16 + fg * 4 + q) * SS + sg[j]] = tanhfast(a1[q] + bia2[1][q]);
          }
        }
      }
    } else if (!last) {
      carr(vN);
    }
    __syncthreads();

    // ---- P5: epilogue(t) + build(t+1); globals already in registers
    {
#pragma unroll
      for (int j = 0; j < 4; ++j) if (eval[j]) {
        const int ii = eidx[j];
        float uv = sm.sU[ii], ov = sm.sO[ii], pv = sm.sH[ii];
        float pm = pv + (ov - pv) * uv;
        out_pmu[obase + ii] = pm;
        float a = avv[j];
        float at2 = pm + (xcar[j] - pm) * a;
        out_att[obase + ii] = at2;
        if (last) {
          out_h[(size_t)n * HH + ii] = at2;
        } else {
          float h = xnv[j] + (at2 - xnv[j]) * m2;
          sm.sH[ii] = h;
          sm.u.im.stacked[stSw[j]] = f2bf(h);
          xcar[j] = xnv[j];
        }
      }
    }
    __syncthreads();
  }
}

extern "C" void kernel_launch(void* const* d_in, const int* in_sizes, int n_in,
                              void* d_out, int out_size, void* d_ws, size_t ws_size,
                              hipStream_t stream)
{
  const float* x    = (const float*)d_in[0];
  const float* hxs  = (const float*)d_in[1];
  const float* att  = (const float*)d_in[2];
  const float* mks  = (const float*)d_in[3];
  const float* pact = (const float*)d_in[4];
  const float* Wr1  = (const float*)d_in[5];
  const float* br1  = (const float*)d_in[6];
  const float* Wr2  = (const float*)d_in[7];
  const float* br2  = (const float*)d_in[8];
  const float* Wu1  = (const float*)d_in[9];
  const float* bu1  = (const float*)d_in[10];
  const float* Wu2  = (const float*)d_in[11];
  const float* bu2  = (const float*)d_in[12];
  const float* Wo1  = (const float*)d_in[13];
  const float* bo1  = (const float*)d_in[14];
  const float* Wo2  = (const float*)d_in[15];
  const float* bo2  = (const float*)d_in[16];

  convgru_mfma<<<dim3(NB), dim3(NTHR), 0, stream>>>(
      x, hxs, att, mks, pact,
      Wr1, br1, Wr2, br2, Wu1, bu1, Wu2, bu2, Wo1, bo1, Wo2, bo2,
      (float*)d_out);
}

// Round 7
// 287.737 us; speedup vs baseline: 1.7335x; 1.7335x over previous
//
#include <hip/hip_runtime.h>
#include <math.h>

// ConvGRU scan, bf16 MFMA 16x16x32, 128 blocks x 512 threads (8 waves).
// Round-5 structure (all waves busy each phase) with:
//  - carr (per-step inp-term class table) weights PRELOADED to registers:
//    removes 864 ds_read_b128/step (was 2/3 of all LDS traffic).
//  - images in additive stride-56-short (112B) layout: bank-conflict-free
//    without XOR swizzle; 3x3 tap offsets fold into ds_read immediates.

#define TT 64
#define NB 128
#define CC 32
#define AA 8
#define SS 49
#define HH 1568
#define KK 288      // 9 taps * 32 channels, all six convs
#define NKB 9
#define NPOS 81
#define IST 56      // shorts per position (112B: 28 banks/pos -> period-8, conflict-free)
#define NTHR 512

typedef short bf16x8 __attribute__((ext_vector_type(8)));
typedef short bf16x4 __attribute__((ext_vector_type(4)));
typedef float f32x4 __attribute__((ext_vector_type(4)));

struct __align__(16) SMEM {
  union {
    short staging[CC * KK];             // 9216 shorts weight scratch
    struct {
      short stacked[NPOS * IST];        // prev (or prev*r)
      short img_u[NPOS * IST];          // u1 / o1 relu output
      short img_r[NPOS * IST];          // r1 relu output
    } im;
  } u;                                  // 13608 shorts
  short wsum[3 * 9 * CC * AA];          // bf16 class-summed inp weights [g][cls][co][ci]
  short cArr[3 * 9 * CC];               // per-step inp term + conv1 bias [g][cls][co]
  float sH[HH];
  float sU[HH];
  float sO[HH];
  float bias[6 * CC];                   // bu1,bu2,br1,br2,bo1,bo2
};

__device__ __forceinline__ short f2bf(float v) {
  union { float f; unsigned u; } a; a.f = v;
  unsigned r = a.u + 0x7FFFu + ((a.u >> 16) & 1u);
  return (short)(r >> 16);
}
__device__ __forceinline__ float b2f(short h) {
  union { unsigned u; float f; } a; a.u = ((unsigned)(unsigned short)h) << 16;
  return a.f;
}
__device__ __forceinline__ float sigm(float v) { return 1.f / (1.f + __expf(-v)); }
__device__ __forceinline__ float tanhfast(float v) { return 2.f / (1.f + __expf(-2.f * v)) - 1.f; }

__device__ __forceinline__ int clsOf(int s) {
  int y = s / 7, x = s - y * 7;
  return (y == 0 ? 0 : (y == 6 ? 6 : 3)) + (x == 0 ? 0 : (x == 6 ? 2 : 1));
}

#define MFMA(A, B, C) __builtin_amdgcn_mfma_f32_16x16x32_bf16((A), (B), (C), 0, 0, 0)

// 9-tap conv GEMM, dual accumulator chains; tap offsets are compile-time
// immediates relative to per-lane base (additive layout).
__device__ __forceinline__ f32x4 conv288(const short* img, const bf16x8 (&fA)[NKB], int base)
{
  f32x4 a0 = {0.f, 0.f, 0.f, 0.f}, a1 = {0.f, 0.f, 0.f, 0.f};
#pragma unroll
  for (int b = 0; b < NKB; b += 2) {
    a0 = MFMA(fA[b], *(const bf16x8*)(img + base + (b / 3) * (9 * IST) + (b % 3) * IST), a0);
    if (b + 1 < NKB)
      a1 = MFMA(fA[b + 1], *(const bf16x8*)(img + base + ((b + 1) / 3) * (9 * IST) + ((b + 1) % 3) * IST), a1);
  }
  return a0 + a1;
}

__global__ __launch_bounds__(NTHR, 2)
void convgru_mfma(const float* __restrict__ x, const float* __restrict__ hxs,
                  const float* __restrict__ att, const float* __restrict__ masks,
                  const float* __restrict__ pact,
                  const float* __restrict__ Wr1, const float* __restrict__ br1,
                  const float* __restrict__ Wr2, const float* __restrict__ br2,
                  const float* __restrict__ Wu1, const float* __restrict__ bu1,
                  const float* __restrict__ Wu2, const float* __restrict__ bu2,
                  const float* __restrict__ Wo1, const float* __restrict__ bo1,
                  const float* __restrict__ Wo2, const float* __restrict__ bo2,
                  float* __restrict__ out)
{
  __shared__ SMEM sm;
  const int n = blockIdx.x;
  const int tid = threadIdx.x;
  const int w = __builtin_amdgcn_readfirstlane(tid >> 6);
  const int lane = tid & 63;
  const int gate = w >> 2;            // 0=u, 1=r
  const int wq = w & 3;
  const int mt = w & 1;
  const int sbase = (wq >> 1) * 2;
  const int stO = w >> 1;
  const int fg = lane >> 4;
  const int col = lane & 15;
  const int co0 = mt * 16 + fg * 4;

  // ---- bias staging
  if (tid < 6 * CC) {
    const float* bsrc[6] = {bu1, bu2, br1, br2, bo1, bo2};
    sm.bias[tid] = bsrc[tid >> 5][tid & 31];
  }

  // ---- weight transpose staging + per-wave A-frag preload (k = tap*32 + pc)
  bf16x8 fG1[NKB], fG2[NKB], fO1[NKB], fO2[NKB];
  {
    const float* wsrc[6] = {Wu1, Wr1, Wo1, Wu2, Wr2, Wo2};
    const int fco = mt * 16 + col;
#pragma unroll
    for (int cv = 0; cv < 6; ++cv) {
      __syncthreads();
      const float* wp = wsrc[cv];
      const int cin = (cv < 3) ? (AA + CC) : CC;
      const int cofs = (cv < 3) ? AA : 0;
      for (int i = tid; i < CC * KK; i += NTHR) {
        int co = i / KK, k = i - co * KK;
        int tap = k >> 5, pc = k & 31;
        sm.u.staging[(co * KK + k) ^ ((co & 7) << 3)] =
            f2bf(wp[(co * cin + cofs + pc) * 9 + tap]);
      }
      __syncthreads();
      auto loadfr = [&](bf16x8 (&dst)[NKB]) {
#pragma unroll
        for (int b = 0; b < NKB; ++b)
          dst[b] = *(const bf16x8*)&sm.u.staging[(fco * KK + b * 32 + fg * 8) ^ ((fco & 7) << 3)];
      };
      if (cv == 0) { if (gate == 0) loadfr(fG1); }
      else if (cv == 1) { if (gate == 1) loadfr(fG1); }
      else if (cv == 2) { loadfr(fO1); }
      else if (cv == 3) { if (gate == 0) loadfr(fG2); }
      else if (cv == 4) { if (gate == 1) loadfr(fG2); }
      else { loadfr(fO2); }
    }
  }
  __syncthreads();

  // ---- zero FULL image extent (borders must stay 0) + Wsum (disjoint regions)
  {
    short* imz = (short*)&sm.u;
    for (int i = tid; i < 3 * NPOS * IST; i += NTHR) imz[i] = 0;
    const float* w1s[3] = {Wu1, Wr1, Wo1};
    for (int e = tid; e < 3 * 9 * CC * AA; e += NTHR) {
      int g = e / 2304, rem = e - g * 2304;
      int cls = rem >> 8;
      int co = (rem >> 3) & 31, ci = e & 7;
      int yt = cls / 3, xt = cls - yt * 3;
      const float* wp = w1s[g] + (co * (AA + CC) + ci) * 9;
      float s = 0.f;
#pragma unroll
      for (int r = 0; r < 3; ++r) {
        if ((yt == 0 && r == 0) || (yt == 2 && r == 2)) continue;
#pragma unroll
        for (int c = 0; c < 3; ++c) {
          if ((xt == 0 && c == 0) || (xt == 2 && c == 2)) continue;
          s += wp[r * 3 + c];
        }
      }
      sm.wsum[e] = f2bf(s);
    }
  }

  // ---- per-lane spatial precompute (t-invariant, additive layout)
  int sg[2], clsAG[2], binG[2], poutG[2]; bool vG[2];
#pragma unroll
  for (int j = 0; j < 2; ++j) {
    int s = (sbase + j) * 16 + col;
    vG[j] = (s < SS); int sc = vG[j] ? s : (SS - 1); sg[j] = sc;
    int y = sc / 7, xx = sc - y * 7;
    int p0 = y * 9 + xx;
    binG[j] = p0 * IST + fg * 8;
    poutG[j] = (p0 + 10) * IST + co0;
    clsAG[j] = ((gate * 9 + clsOf(sc)) << 5) + co0;
  }
  int sOv, binO, poutO, clsAO; bool vO;
  {
    int s = stO * 16 + col;
    vO = (s < SS); int sc = vO ? s : (SS - 1); sOv = sc;
    int y = sc / 7, xx = sc - y * 7;
    int p0 = y * 9 + xx;
    binO = p0 * IST + fg * 8;
    poutO = (p0 + 10) * IST + co0;
    clsAO = ((2 * 9 + clsOf(sc)) << 5) + co0;
  }

  // ---- epilogue precompute
  int eidx[4], stSw[4]; bool eval[4];
#pragma unroll
  for (int j = 0; j < 4; ++j) {
    int i = tid + j * NTHR;
    eval[j] = (i < HH);
    int ii = eval[j] ? i : 0;
    eidx[j] = ii;
    int co = ii / SS, s = ii - co * SS;
    int y = s / 7, xx = s - y * 7;
    stSw[j] = (y * 9 + xx + 10) * IST + co;
  }

  float* out_pmu = out;
  float* out_att = out + (size_t)TT * NB * HH;
  float* out_h   = out + (size_t)2 * TT * NB * HH;

  __syncthreads();

  // conv2 biases to registers
  f32x4 biaG2, biaO2;
#pragma unroll
  for (int q = 0; q < 4; ++q) {
    biaG2[q] = sm.bias[(gate * 2 + 1) * 32 + co0 + q];
    biaO2[q] = sm.bias[5 * 32 + co0 + q];
  }

  // ---- carr weight PRELOAD to registers (kills per-step wsum re-reads)
  const int e1 = tid + NTHR;
  const bool ok1 = (e1 < 3 * 9 * CC);
  bf16x8 wR0 = *(const bf16x8*)&sm.wsum[tid << 3];
  float bR0 = sm.bias[((tid / 288) << 6) + (tid & 31)];
  bf16x8 wR1 = ok1 ? *(const bf16x8*)&sm.wsum[e1 << 3] : wR0;
  float bR1 = ok1 ? sm.bias[((e1 / 288) << 6) + (e1 & 31)] : 0.f;

  auto carr = [&](const float (&v)[8]) {
    float acc = bR0;
#pragma unroll
    for (int q = 0; q < 8; ++q) acc = fmaf(b2f(wR0[q]), v[q], acc);
    sm.cArr[tid] = f2bf(acc);
    if (ok1) {
      float a2 = bR1;
#pragma unroll
      for (int q = 0; q < 8; ++q) a2 = fmaf(b2f(wR1[q]), v[q], a2);
      sm.cArr[e1] = f2bf(a2);
    }
  };

  // ---- step-0 build
  float xcar[4];
  {
    const float m0 = masks[n];
    const float* x0 = x + (size_t)n * HH;
    const float* h0 = hxs + (size_t)n * HH;
#pragma unroll
    for (int j = 0; j < 4; ++j) if (eval[j]) {
      float xv = x0[eidx[j]];
      float h = h0[eidx[j]] * m0 + xv * (1.f - m0);
      sm.sH[eidx[j]] = h;
      sm.u.im.stacked[stSw[j]] = f2bf(h);
      xcar[j] = xv;
    }
    float v0[8];
    const float* pa0 = pact + (size_t)n * AA;
#pragma unroll
    for (int q = 0; q < 8; ++q) v0[q] = pa0[q] * m0;
    carr(v0);
  }
  __syncthreads();

  for (int t = 0; t < TT; ++t) {
    const bool last = (t == TT - 1);
    const size_t obase = ((size_t)(t * NB) + n) * HH;

    // prefetch: att(t), x(t+1), masks(t+1), pact(t+1) — consumed in P4/P5
    const float* atp = att + obase;
    const int tn = last ? t : (t + 1);
    const float* xnp = x + ((size_t)(tn * NB) + n) * HH;
    float xnv[4], avv[4];
#pragma unroll
    for (int j = 0; j < 4; ++j) { avv[j] = atp[eidx[j]]; xnv[j] = xnp[eidx[j]]; }
    const float m2 = last ? 0.f : masks[(t + 1) * NB + n];
    float vN[8];
    const float* pap = pact + ((size_t)(tn * NB) + n) * AA;
#pragma unroll
    for (int q = 0; q < 8; ++q) vN[q] = pap[q] * m2;

    // P1: u1 / r1 (+cArr class term, relu) -> img_u / img_r
    {
      short* imgOut = gate ? sm.u.im.img_r : sm.u.im.img_u;
#pragma unroll
      for (int j = 0; j < 2; ++j) {
        f32x4 a = conv288(sm.u.im.stacked, fG1, binG[j]);
        if (vG[j]) {
          bf16x4 c4 = *(const bf16x4*)&sm.cArr[clsAG[j]];
          bf16x4 pk;
#pragma unroll
          for (int q = 0; q < 4; ++q) pk[q] = f2bf(fmaxf(a[q] + b2f(c4[q]), 0.f));
          *(bf16x4*)&imgOut[poutG[j]] = pk;
        }
      }
    }
    __syncthreads();

    // P2: u2 -> sigmoid -> sU ; r2 -> sigmoid*prev -> stacked (in place)
    if (gate == 0) {
#pragma unroll
      for (int j = 0; j < 2; ++j) {
        f32x4 a = conv288(sm.u.im.img_u, fG2, binG[j]);
        if (vG[j]) {
#pragma unroll
          for (int q = 0; q < 4; ++q)
            sm.sU[(co0 + q) * SS + sg[j]] = sigm(a[q] + biaG2[q]);
        }
      }
    } else {
#pragma unroll
      for (int j = 0; j < 2; ++j) {
        f32x4 a = conv288(sm.u.im.img_r, fG2, binG[j]);
        if (vG[j]) {
          bf16x4 pk;
#pragma unroll
          for (int q = 0; q < 4; ++q) {
            float rv = sigm(a[q] + biaG2[q]);
            pk[q] = f2bf(sm.sH[(co0 + q) * SS + sg[j]] * rv);
          }
          *(bf16x4*)&sm.u.im.stacked[poutG[j]] = pk;
        }
      }
    }
    __syncthreads();

    // P3: o1 on stacked2 (+cArr class term, relu) -> img_u, 8 jobs / 8 waves
    {
      f32x4 a = conv288(sm.u.im.stacked, fO1, binO);
      if (vO) {
        bf16x4 c4 = *(const bf16x4*)&sm.cArr[clsAO];
        bf16x4 pk;
#pragma unroll
        for (int q = 0; q < 4; ++q) pk[q] = f2bf(fmaxf(a[q] + b2f(c4[q]), 0.f));
        *(bf16x4*)&sm.u.im.img_u[poutO] = pk;
      }
    }
    __syncthreads();

    // P4: o2 -> tanh -> sO; then cArr(t+1) from registers (last reader was P3)
    {
      f32x4 a = conv288(sm.u.im.img_u, fO2, binO);
      if (vO) {
#pragma unroll
        for (int q = 0; q < 4; ++q)
          sm.sO[(co0 + q) * SS + sOv] = tanhfast(a[q] + biaO2[q]);
      }
      if (!last) carr(vN);
    }
    __syncthreads();

    // P5: epilogue(t) + build(t+1); globals already in registers
    {
#pragma unroll
      for (int j = 0; j < 4; ++j) if (eval[j]) {
        const int ii = eidx[j];
        float uv = sm.sU[ii], ov = sm.sO[ii], pv = sm.sH[ii];
        float pm = pv + (ov - pv) * uv;
        out_pmu[obase + ii] = pm;
        float a = avv[j];
        float at2 = pm + (xcar[j] - pm) * a;
        out_att[obase + ii] = at2;
        if (last) {
          out_h[(size_t)n * HH + ii] = at2;
        } else {
          float h = xnv[j] + (at2 - xnv[j]) * m2;
          sm.sH[ii] = h;
          sm.u.im.stacked[stSw[j]] = f2bf(h);
          xcar[j] = xnv[j];
        }
      }
    }
    __syncthreads();
  }
}

extern "C" void kernel_launch(void* const* d_in, const int* in_sizes, int n_in,
                              void* d_out, int out_size, void* d_ws, size_t ws_size,
                              hipStream_t stream)
{
  const float* x    = (const float*)d_in[0];
  const float* hxs  = (const float*)d_in[1];
  const float* att  = (const float*)d_in[2];
  const float* mks  = (const float*)d_in[3];
  const float* pact = (const float*)d_in[4];
  const float* Wr1  = (const float*)d_in[5];
  const float* br1  = (const float*)d_in[6];
  const float* Wr2  = (const float*)d_in[7];
  const float* br2  = (const float*)d_in[8];
  const float* Wu1  = (const float*)d_in[9];
  const float* bu1  = (const float*)d_in[10];
  const float* Wu2  = (const float*)d_in[11];
  const float* bu2  = (const float*)d_in[12];
  const float* Wo1  = (const float*)d_in[13];
  const float* bo1  = (const float*)d_in[14];
  const float* Wo2  = (const float*)d_in[15];
  const float* bo2  = (const float*)d_in[16];

  convgru_mfma<<<dim3(NB), dim3(NTHR), 0, stream>>>(
      x, hxs, att, mks, pact,
      Wr1, br1, Wr2, br2, Wu1, bu1, Wu2, bu2, Wo1, bo1, Wo2, bo2,
      (float*)d_out);
}